// Round 3
// baseline (2467.818 us; speedup 1.0000x reference)
//
#include <hip/hip_runtime.h>
#include <hip/hip_bf16.h>

#define DINL __device__ __forceinline__

namespace {

typedef unsigned long long u64;

constexpr int Tn = 256;   // sequence length
constexpr int Bn = 64;    // batch
constexpr int HDn = 256;  // per-direction hidden
constexpr int Kt = 20;    // tagset
constexpr int STOPt = 19;
constexpr int STARTt = 18;
constexpr float NEGV = -10000.0f;

DINL float sigm(float x) { return 1.0f / (1.0f + __expf(-x)); }
DINL float tanh_f(float x) {
  float ax = fabsf(x);
  float e = __expf(-2.0f * ax);       // in (0,1]
  float t = (1.0f - e) / (1.0f + e);
  return x < 0.0f ? -t : t;
}

DINL u64 agent_ld64(const u64* p) {
  return __hip_atomic_load(p, __ATOMIC_RELAXED, __HIP_MEMORY_SCOPE_AGENT);
}
DINL void agent_st64(u64* p, u64 v) {
  __hip_atomic_store(p, v, __ATOMIC_RELAXED, __HIP_MEMORY_SCOPE_AGENT);
}

// ---------------- K0: clear h-epoch pairs (replay safety) --------------------
// Plain stores; end-of-dispatch L2 writeback makes zeros visible at the
// coherence point before k_lstm's sc1 polls start (stream-serialized).
__global__ void k_clear(uint4* p) {
  size_t i = (size_t)blockIdx.x * 256 + threadIdx.x;   // 4096*256 threads
  const uint4 z = {0, 0, 0, 0};
#pragma unroll
  for (int j = 0; j < 4; ++j) p[i + (size_t)j * 4096 * 256] = z;
}

// ---------------- K1: transpose/concat W_ih into Wt[300][2048] ---------------
__global__ void k_wt(const float* __restrict__ wf, const float* __restrict__ wb,
                     float* __restrict__ Wt) {
  int idx = blockIdx.x * 256 + threadIdx.x;
  if (idx >= 300 * 2048) return;
  int k = idx >> 11, n = idx & 2047;
  const float* w = (n < 1024) ? wf : wb;
  int nn = n & 1023;
  Wt[idx] = w[nn * 300 + k];
}

// ---------------- K2: x_proj = gather(embeds) @ W_ih^T + b -------------------
// C[16384, 2048], row m = t*64 + b. Tile 64(M) x 128(N), BK=20, 256 threads.
__global__ __launch_bounds__(256) void k_xproj(
    const int* __restrict__ sentence, const float* __restrict__ table,
    const float* __restrict__ Wt, const float* __restrict__ b_f,
    const float* __restrict__ b_b, float* __restrict__ xproj) {
  __shared__ float As[20][68];    // A^T tile: [kk][row(b)]
  __shared__ float Bs[20][136];   // [kk][col]
  __shared__ int tok[64];

  int tid = threadIdx.x;
  int t = blockIdx.x;             // one time index per M-tile (64 rows = 64 b)
  int n0 = blockIdx.y * 128;

  if (tid < 64) tok[tid] = sentence[tid * Tn + t];  // sentence[b][t]
  __syncthreads();

  int ty = tid >> 4, tx = tid & 15;   // 16x16 threads; micro-tile 4(M) x 8(N)
  float acc[4][8];
#pragma unroll
  for (int i = 0; i < 4; ++i)
#pragma unroll
    for (int j = 0; j < 8; ++j) acc[i][j] = 0.0f;

  for (int k0 = 0; k0 < 300; k0 += 20) {
    // A tile: 64 rows x 20 k (gathered embedding rows)
#pragma unroll
    for (int i = 0; i < 5; ++i) {
      int idx = i * 256 + tid;        // 0..1279
      int r = idx / 20, kk = idx % 20;
      As[kk][r] = table[tok[r] * 300 + k0 + kk];
    }
    // B tile: 20 k x 128 n (from pre-transposed Wt, coalesced)
#pragma unroll
    for (int i = 0; i < 10; ++i) {
      int idx = i * 256 + tid;        // 0..2559
      int kk = idx >> 7, c = idx & 127;
      Bs[kk][c] = Wt[(k0 + kk) * 2048 + n0 + c];
    }
    __syncthreads();
#pragma unroll
    for (int kk = 0; kk < 20; ++kk) {
      float4 a4 = *(const float4*)&As[kk][ty * 4];
      float4 b4a = *(const float4*)&Bs[kk][tx * 8];
      float4 b4b = *(const float4*)&Bs[kk][tx * 8 + 4];
      float av[4] = {a4.x, a4.y, a4.z, a4.w};
      float bvv[8] = {b4a.x, b4a.y, b4a.z, b4a.w, b4b.x, b4b.y, b4b.z, b4b.w};
#pragma unroll
      for (int i = 0; i < 4; ++i)
#pragma unroll
        for (int j = 0; j < 8; ++j) acc[i][j] += av[i] * bvv[j];
    }
    __syncthreads();
  }

  float bias[8];
#pragma unroll
  for (int j = 0; j < 8; ++j) {
    int n = n0 + tx * 8 + j;
    bias[j] = (n < 1024) ? b_f[n] : b_b[n - 1024];
  }
#pragma unroll
  for (int i = 0; i < 4; ++i) {
    size_t m = (size_t)t * 64 + ty * 4 + i;   // row = (t, b=ty*4+i)
    float* dst = &xproj[m * 2048 + n0 + tx * 8];
    float4 v0 = {acc[i][0] + bias[0], acc[i][1] + bias[1], acc[i][2] + bias[2],
                 acc[i][3] + bias[3]};
    float4 v1 = {acc[i][4] + bias[4], acc[i][5] + bias[5], acc[i][6] + bias[6],
                 acc[i][7] + bias[7]};
    *(float4*)dst = v0;
    *(float4*)(dst + 4) = v1;
  }
}

// ---------------- K3: persistent bidirectional LSTM --------------------------
// 128 blocks x 512 thr. gid = bid&7 -> (dir, batch-group); s = bid>>3 (slice).
// W slice register-stationary (thread (row=tid>>3, kc=tid&7) holds 32 floats).
// h exchanged as SELF-VALIDATING {f32 h, u32 epoch} 8B pairs via relaxed
// agent-scope atomics: no fence, no flags, no store-ack barrier. Consumers
// poll their own pairs directly. 2 barriers/step.
__global__ __launch_bounds__(512) void k_lstm(
    const float* __restrict__ whh_f, const float* __restrict__ whh_b,
    const float* __restrict__ xproj, u64* __restrict__ h_ep) {
  __shared__ __align__(16) float hl[16 * 256];  // staged h chunk, granule-XOR
  __shared__ float gl[64 * 17];                 // reduced gates [row][b]

  int tid = threadIdx.x;
  int bid = blockIdx.x;
  int gid = bid & 7;        // dir = gid>>2, bg = gid&3 (XCD-affine: perf only)
  int s = bid >> 3;         // slice 0..15 (16 hidden cols each)
  int dir = gid >> 2;
  int bg = gid & 3;
  const float* whh = dir ? whh_b : whh_f;

  int row = tid >> 3;       // local gate row 0..63 (g = row>>4, c = row&15)
  int kc = tid & 7;         // k-chunk of 32
  int g = row >> 4, c = row & 15;

  // --- W slice into registers (one-time, 8 x b128 per thread)
  float w[32];
  {
    const float* src =
        whh + ((size_t)(g * 256 + s * 16 + c)) * 256 + kc * 32;
#pragma unroll
    for (int j = 0; j < 8; ++j) {
      float4 v = *(const float4*)(src + j * 4);
      w[j * 4 + 0] = v.x; w[j * 4 + 1] = v.y;
      w[j * 4 + 2] = v.z; w[j * 4 + 3] = v.w;
    }
  }

  int ub = tid >> 4, ucol = tid & 15;   // update-phase mapping (tid<256)
  float c_reg = 0.0f;

  // staging mapping: thread -> batch row sb, 8-col chunk sq8 (8 pairs = 64B)
  int sb = tid >> 5;          // 0..15
  int sq8 = tid & 31;         // 0..31
  int gq0 = 2 * sq8, gq1 = gq0 + 1;   // two float4 granules
  int d0 = (gq0 & ~7) | ((gq0 ^ (gq0 >> 3)) & 7);
  int d1 = (gq1 & ~7) | ((gq1 ^ (gq1 >> 3)) & 7);

  for (int st = 0; st < Tn; ++st) {
    int xt = dir ? (Tn - 1 - st) : st;

    // prefetch x-projection gates (independent -> overlaps the poll)
    float xp0 = 0, xp1 = 0, xp2 = 0, xp3 = 0;
    if (tid < 256) {
      size_t base = ((size_t)(xt * 64 + bg * 16 + ub)) * 2048 + dir * 1024 +
                    s * 16 + ucol;
      xp0 = xproj[base];
      xp1 = xproj[base + 256];
      xp2 = xproj[base + 512];
      xp3 = xproj[base + 768];
    }

    float acc[16];
#pragma unroll
    for (int b = 0; b < 16; ++b) acc[b] = 0.0f;

    if (st > 0) {
      int pt = dir ? (xt + 1) : (xt - 1);
      const u64* p = h_ep +
                     ((size_t)(dir * Tn + pt) * 64 + bg * 16 + sb) * 256 +
                     sq8 * 8;
      // poll own 8 pairs until all carry epoch == st (producer wrote st)
      u64 v[8];
      unsigned tgt = (unsigned)st;
      for (;;) {
        bool ok = true;
#pragma unroll
        for (int j = 0; j < 8; ++j) v[j] = agent_ld64(p + j);
#pragma unroll
        for (int j = 0; j < 8; ++j) ok &= ((unsigned)(v[j] >> 32) == tgt);
        if (ok) break;
        __builtin_amdgcn_s_sleep(1);
      }
      float4 a, bq;
      a.x = __uint_as_float((unsigned)v[0]);
      a.y = __uint_as_float((unsigned)v[1]);
      a.z = __uint_as_float((unsigned)v[2]);
      a.w = __uint_as_float((unsigned)v[3]);
      bq.x = __uint_as_float((unsigned)v[4]);
      bq.y = __uint_as_float((unsigned)v[5]);
      bq.z = __uint_as_float((unsigned)v[6]);
      bq.w = __uint_as_float((unsigned)v[7]);
      *(float4*)&hl[sb * 256 + d0 * 4] = a;
      *(float4*)&hl[sb * 256 + d1 * 4] = bq;
      __syncthreads();  // B2: hl ready (prev-step hl reads done before B3(st-1))
      // GEMV: h from LDS (8-way broadcast, XOR-permuted granules), W in regs
#pragma unroll
      for (int b = 0; b < 16; ++b) {
        float sacc = 0.0f;
#pragma unroll
        for (int j = 0; j < 8; ++j) {
          // granule gq = kc*8+j stored at kc*8 + (j^kc)
          float4 hv = *(const float4*)&hl[b * 256 + kc * 32 + (j ^ kc) * 4];
          sacc += w[j * 4 + 0] * hv.x + w[j * 4 + 1] * hv.y +
                  w[j * 4 + 2] * hv.z + w[j * 4 + 3] * hv.w;
        }
        acc[b] = sacc;
      }
    }

    // butterfly reduce over kc (lanes differing in tid&7)
#pragma unroll
    for (int m = 1; m < 8; m <<= 1) {
#pragma unroll
      for (int b = 0; b < 16; ++b) acc[b] += __shfl_xor(acc[b], m, 64);
    }
    // each lane now holds gate[row][0..15]; lane kc writes batches 2kc,2kc+1
    gl[row * 17 + 2 * kc] = acc[2 * kc];
    gl[row * 17 + 2 * kc + 1] = acc[2 * kc + 1];
    __syncthreads();  // B3: gl ready

    if (tid < 256) {
      float gi = gl[(0 * 16 + ucol) * 17 + ub] + xp0;
      float gf = gl[(1 * 16 + ucol) * 17 + ub] + xp1;
      float gg = gl[(2 * 16 + ucol) * 17 + ub] + xp2;
      float go = gl[(3 * 16 + ucol) * 17 + ub] + xp3;
      c_reg = sigm(gf) * c_reg + sigm(gi) * tanh_f(gg);
      float h = sigm(go) * tanh_f(c_reg);
      u64 pk = ((u64)(unsigned)(st + 1) << 32) | (u64)__float_as_uint(h);
      agent_st64(&h_ep[((size_t)(dir * Tn + xt) * 64 + bg * 16 + ub) * 256 +
                       s * 16 + ucol],
                 pk);
    }
    // no B4, no flag: pairs are self-validating
  }
}

// ---------------- K4: feats = concat(hf,hb) @ W_out^T + b_out ----------------
// one block per t; 256 thr = 64 b x 4 k-groups(5)
__global__ __launch_bounds__(256) void k_feats(const u64* __restrict__ h_ep,
                                               const float* __restrict__ Wout,
                                               const float* __restrict__ bout,
                                               float* __restrict__ feats) {
  __shared__ float Wl[20 * 512];   // 40KB
  __shared__ float hlf[64 * 256];  // 64KB, XOR-swizzled

  int tid = threadIdx.x;
  int t = blockIdx.x;
  for (int i = tid; i < 20 * 512; i += 256) Wl[i] = Wout[i];

  float acc[5] = {0, 0, 0, 0, 0};
  int b = tid & 63, kg5 = tid >> 6;
  int swz = b & 7;

  for (int d = 0; d < 2; ++d) {
    __syncthreads();
    const u64* hsrc = h_ep + ((size_t)(d * Tn + t)) * 64 * 256;
#pragma unroll 8
    for (int i = 0; i < 64; ++i) {
      int idx = i * 256 + tid;
      int hb = idx >> 8, k = idx & 255;
      u64 pk = hsrc[idx];
      hlf[hb * 256 + 4 * ((k >> 2) ^ (hb & 7)) + (k & 3)] =
          __uint_as_float((unsigned)pk);
    }
    __syncthreads();
    for (int jg = 0; jg < 64; ++jg) {
      float4 hv = *(const float4*)&hlf[b * 256 + 4 * (jg ^ swz)];
#pragma unroll
      for (int kk = 0; kk < 5; ++kk) {
        int krow = kg5 * 5 + kk;
        float4 wvv = *(const float4*)&Wl[krow * 512 + d * 256 + jg * 4];
        acc[kk] += hv.x * wvv.x + hv.y * wvv.y + hv.z * wvv.z + hv.w * wvv.w;
      }
    }
  }
#pragma unroll
  for (int kk = 0; kk < 5; ++kk) {
    int krow = kg5 * 5 + kk;
    feats[((size_t)b * Tn + t) * Kt + krow] = acc[kk] + bout[krow];
  }
}

// ---------------- K5: Viterbi decode, one wave per batch element -------------
__global__ __launch_bounds__(64) void k_viterbi(const float* __restrict__ feats,
                                                const float* __restrict__ trans,
                                                const int* __restrict__ length,
                                                float* __restrict__ out) {
  __shared__ float tr[400];
  __shared__ float fv[20];
  __shared__ float term[20];
  __shared__ unsigned char bps[256][20];

  int b = blockIdx.x;
  int lane = threadIdx.x;
  for (int i = lane; i < 400; i += 64) tr[i] = trans[i];
  if (lane < 20) fv[lane] = (lane == STARTt) ? 0.0f : NEGV;
  int len = length[b];
  __syncthreads();

  for (int t = 0; t < Tn; ++t) {
    float nf = 0.0f;
    int bp = 0;
    if (lane < 20) {
      if (t < len) {
        float vmax = -3.4e38f;
        int pb = 0;
#pragma unroll
        for (int p = 0; p < 20; ++p) {
          float v = fv[p] + tr[lane * 20 + p];
          if (v > vmax) { vmax = v; pb = p; }   // strict > == first-argmax
        }
        nf = vmax + feats[((size_t)b * Tn + t) * Kt + lane];
        bp = pb;
      } else {
        nf = fv[lane];
        bp = lane;
      }
    }
    __syncthreads();
    if (lane < 20) {
      fv[lane] = nf;
      bps[t][lane] = (unsigned char)bp;
    }
    __syncthreads();
  }

  if (lane < 20) term[lane] = fv[lane] + tr[STOPt * 20 + lane];
  __syncthreads();
  if (lane == 0) {
    float smax = term[0];
    int last = 0;
    for (int p = 1; p < 20; ++p)
      if (term[p] > smax) { smax = term[p]; last = p; }
    out[b] = smax;                     // viterbi score
    int tag = last;
    for (int t = Tn - 1; t >= 0; --t) {
      out[64 + b * Tn + t] = (float)tag;
      tag = bps[t][tag];
    }
  }
}

}  // namespace

extern "C" void kernel_launch(void* const* d_in, const int* in_sizes, int n_in,
                              void* d_out, int out_size, void* d_ws,
                              size_t ws_size, hipStream_t stream) {
  const int* sentence = (const int*)d_in[0];
  const int* length = (const int*)d_in[1];
  const float* table = (const float*)d_in[2];
  const float* w_ih_f = (const float*)d_in[3];
  const float* w_hh_f = (const float*)d_in[4];
  const float* b_f = (const float*)d_in[5];
  const float* w_ih_b = (const float*)d_in[6];
  const float* w_hh_b = (const float*)d_in[7];
  const float* b_b = (const float*)d_in[8];
  const float* W_out = (const float*)d_in[9];
  const float* b_out = (const float*)d_in[10];
  const float* trans = (const float*)d_in[11];
  float* out = (float*)d_out;

  // workspace layout (floats)
  float* ws = (float*)d_ws;
  float* xproj = ws;                                  // 33,554,432 f
  u64* h_ep = (u64*)(ws + (size_t)33554432);          // 8,388,608 u64 (67 MB)
  float* Wt = ws + (size_t)33554432 + 16777216;       // 614,400 f
  float* feats = Wt + (size_t)300 * 2048;             // 327,680 f
  (void)ws_size; (void)in_sizes; (void)n_in; (void)out_size;

  k_clear<<<dim3(4096), dim3(256), 0, stream>>>((uint4*)h_ep);
  k_wt<<<dim3(2400), dim3(256), 0, stream>>>(w_ih_f, w_ih_b, Wt);
  k_xproj<<<dim3(256, 16), dim3(256), 0, stream>>>(sentence, table, Wt, b_f,
                                                   b_b, xproj);
  k_lstm<<<dim3(128), dim3(512), 0, stream>>>(w_hh_f, w_hh_b, xproj, h_ep);
  k_feats<<<dim3(256), dim3(256), 0, stream>>>(h_ep, W_out, b_out, feats);
  k_viterbi<<<dim3(64), dim3(64), 0, stream>>>(feats, trans, length, out);
}

// Round 4
// 2179.820 us; speedup vs baseline: 1.1321x; 1.1321x over previous
//
#include <hip/hip_runtime.h>
#include <hip/hip_bf16.h>

#define DINL __device__ __forceinline__

namespace {

typedef unsigned long long u64;

constexpr int Tn = 256;   // sequence length
constexpr int Bn = 64;    // batch
constexpr int HDn = 256;  // per-direction hidden
constexpr int Kt = 20;    // tagset
constexpr int STOPt = 19;
constexpr int STARTt = 18;
constexpr float NEGV = -10000.0f;

DINL float sigm(float x) { return 1.0f / (1.0f + __expf(-x)); }
DINL float tanh_f(float x) {
  float ax = fabsf(x);
  float e = __expf(-2.0f * ax);       // in (0,1]
  float t = (1.0f - e) / (1.0f + e);
  return x < 0.0f ? -t : t;
}

DINL u64 agent_ld64(const u64* p) {
  return __hip_atomic_load(p, __ATOMIC_RELAXED, __HIP_MEMORY_SCOPE_AGENT);
}
DINL void agent_st64(u64* p, u64 v) {
  __hip_atomic_store(p, v, __ATOMIC_RELAXED, __HIP_MEMORY_SCOPE_AGENT);
}

// ---------------- K0: clear h-epoch pairs (replay safety) --------------------
__global__ void k_clear(uint4* p) {
  size_t i = (size_t)blockIdx.x * 256 + threadIdx.x;   // 4096*256 threads
  const uint4 z = {0, 0, 0, 0};
#pragma unroll
  for (int j = 0; j < 4; ++j) p[i + (size_t)j * 4096 * 256] = z;
}

// ---------------- K1: transpose/concat W_ih into Wt[300][2048] ---------------
__global__ void k_wt(const float* __restrict__ wf, const float* __restrict__ wb,
                     float* __restrict__ Wt) {
  int idx = blockIdx.x * 256 + threadIdx.x;
  if (idx >= 300 * 2048) return;
  int k = idx >> 11, n = idx & 2047;
  const float* w = (n < 1024) ? wf : wb;
  int nn = n & 1023;
  Wt[idx] = w[nn * 300 + k];
}

// ---------------- K2: x_proj = gather(embeds) @ W_ih^T + b -------------------
// C[16384, 2048], row m = t*64 + b. Tile 64(M) x 128(N), BK=20, 256 threads.
__global__ __launch_bounds__(256) void k_xproj(
    const int* __restrict__ sentence, const float* __restrict__ table,
    const float* __restrict__ Wt, const float* __restrict__ b_f,
    const float* __restrict__ b_b, float* __restrict__ xproj) {
  __shared__ float As[20][68];    // A^T tile: [kk][row(b)]
  __shared__ float Bs[20][136];   // [kk][col]
  __shared__ int tok[64];

  int tid = threadIdx.x;
  int t = blockIdx.x;             // one time index per M-tile (64 rows = 64 b)
  int n0 = blockIdx.y * 128;

  if (tid < 64) tok[tid] = sentence[tid * Tn + t];  // sentence[b][t]
  __syncthreads();

  int ty = tid >> 4, tx = tid & 15;   // 16x16 threads; micro-tile 4(M) x 8(N)
  float acc[4][8];
#pragma unroll
  for (int i = 0; i < 4; ++i)
#pragma unroll
    for (int j = 0; j < 8; ++j) acc[i][j] = 0.0f;

  for (int k0 = 0; k0 < 300; k0 += 20) {
#pragma unroll
    for (int i = 0; i < 5; ++i) {
      int idx = i * 256 + tid;        // 0..1279
      int r = idx / 20, kk = idx % 20;
      As[kk][r] = table[tok[r] * 300 + k0 + kk];
    }
#pragma unroll
    for (int i = 0; i < 10; ++i) {
      int idx = i * 256 + tid;        // 0..2559
      int kk = idx >> 7, c = idx & 127;
      Bs[kk][c] = Wt[(k0 + kk) * 2048 + n0 + c];
    }
    __syncthreads();
#pragma unroll
    for (int kk = 0; kk < 20; ++kk) {
      float4 a4 = *(const float4*)&As[kk][ty * 4];
      float4 b4a = *(const float4*)&Bs[kk][tx * 8];
      float4 b4b = *(const float4*)&Bs[kk][tx * 8 + 4];
      float av[4] = {a4.x, a4.y, a4.z, a4.w};
      float bvv[8] = {b4a.x, b4a.y, b4a.z, b4a.w, b4b.x, b4b.y, b4b.z, b4b.w};
#pragma unroll
      for (int i = 0; i < 4; ++i)
#pragma unroll
        for (int j = 0; j < 8; ++j) acc[i][j] += av[i] * bvv[j];
    }
    __syncthreads();
  }

  float bias[8];
#pragma unroll
  for (int j = 0; j < 8; ++j) {
    int n = n0 + tx * 8 + j;
    bias[j] = (n < 1024) ? b_f[n] : b_b[n - 1024];
  }
#pragma unroll
  for (int i = 0; i < 4; ++i) {
    size_t m = (size_t)t * 64 + ty * 4 + i;   // row = (t, b=ty*4+i)
    float* dst = &xproj[m * 2048 + n0 + tx * 8];
    float4 v0 = {acc[i][0] + bias[0], acc[i][1] + bias[1], acc[i][2] + bias[2],
                 acc[i][3] + bias[3]};
    float4 v1 = {acc[i][4] + bias[4], acc[i][5] + bias[5], acc[i][6] + bias[6],
                 acc[i][7] + bias[7]};
    *(float4*)dst = v0;
    *(float4*)(dst + 4) = v1;
  }
}

// ---------------- K3: persistent bidirectional LSTM --------------------------
// 256 blocks x 128 thr. gid = bid&7 -> (dir, bg); s = bid>>3 in 0..31 (8 cols).
// Thread (c = tid>>4 in 0..7, kc = tid&15): owns ALL 4 gates of hidden col
// s*8+c over k-chunk {granules kc+16*jj}. W in regs (4 gates x 4 float4 = 64).
// Each ds_read_b128 of h feeds 16 FMAs (was 4) -> LDS-issue load cut 4x.
// kc-reduction: register-halving butterfly ending with lane kc holding the
// 4 gates of batch b=kc -> update fully lane-local. 2 barriers/step.
__global__ __launch_bounds__(128) void k_lstm(
    const float* __restrict__ whh_f, const float* __restrict__ whh_b,
    const float* __restrict__ xproj, u64* __restrict__ h_ep) {
  __shared__ __align__(16) float hl[16 * 256];  // 16 batches x 256 k (16KB)

  int tid = threadIdx.x;
  int bid = blockIdx.x;
  int gid = bid & 7;        // dir = gid>>2, bg = gid&3 (XCD-affine grouping)
  int s = bid >> 3;         // slice 0..31 (8 hidden cols each)
  int dir = gid >> 2;
  int bg = gid & 3;
  const float* whh = dir ? whh_b : whh_f;

  int c = tid >> 4;         // hidden-col within slice, 0..7
  int kc = tid & 15;        // k-partition (16 interleaved granules of 4)

  // --- W into registers: w4[gate][jj] = W[g*256 + s*8 + c][ (kc+16jj)*4 .. +4 )
  float4 w4[4][4];
#pragma unroll
  for (int g = 0; g < 4; ++g) {
    const float* src = whh + ((size_t)(g * 256 + s * 8 + c)) * 256;
#pragma unroll
    for (int jj = 0; jj < 4; ++jj)
      w4[g][jj] = *(const float4*)(src + ((kc + (jj << 4)) << 2));
  }

  float c_reg = 0.0f;

  for (int st = 0; st < Tn; ++st) {
    int xt = dir ? (Tn - 1 - st) : st;

    // prefetch x-projection gates (independent -> overlaps the poll)
    float xp[4];
    {
      size_t base = ((size_t)(xt * 64 + bg * 16 + kc)) * 2048 + dir * 1024 +
                    s * 8 + c;
#pragma unroll
      for (int g = 0; g < 4; ++g) xp[g] = xproj[base + g * 256];
    }

    float acc[16][4];
#pragma unroll
    for (int b = 0; b < 16; ++b)
#pragma unroll
      for (int g = 0; g < 4; ++g) acc[b][g] = 0.0f;

    if (st > 0) {
      int pt = dir ? (xt + 1) : (xt - 1);
      const u64* hsrc =
          h_ep + ((size_t)(dir * Tn + pt) * 64 + bg * 16) * 256;
      // poll + gather 8 granules (lane-linear: G = tid + 128*i)
      float4 gv[8];
      unsigned tgt = (unsigned)st;
      for (;;) {
        bool ok = true;
#pragma unroll
        for (int i = 0; i < 8; ++i) {
          const u64* p = hsrc + (size_t)(tid + (i << 7)) * 4;
          u64 p0 = agent_ld64(p + 0);
          u64 p1 = agent_ld64(p + 1);
          u64 p2 = agent_ld64(p + 2);
          u64 p3 = agent_ld64(p + 3);
          ok &= ((unsigned)(p0 >> 32) == tgt) & ((unsigned)(p1 >> 32) == tgt) &
                ((unsigned)(p2 >> 32) == tgt) & ((unsigned)(p3 >> 32) == tgt);
          gv[i].x = __uint_as_float((unsigned)p0);
          gv[i].y = __uint_as_float((unsigned)p1);
          gv[i].z = __uint_as_float((unsigned)p2);
          gv[i].w = __uint_as_float((unsigned)p3);
        }
        if (ok) break;
        __builtin_amdgcn_s_sleep(1);
      }
      __syncthreads();  // B1: previous step's hl readers done
#pragma unroll
      for (int i = 0; i < 8; ++i)
        *(float4*)&hl[(tid + (i << 7)) << 2] = gv[i];
      __syncthreads();  // B2: hl ready

      // GEMV: each b128 read feeds 16 FMAs (4 gates x 4 k)
#pragma unroll
      for (int b = 0; b < 16; ++b) {
#pragma unroll
        for (int jj = 0; jj < 4; ++jj) {
          float4 hv = *(const float4*)&hl[b * 256 + ((kc + (jj << 4)) << 2)];
#pragma unroll
          for (int g = 0; g < 4; ++g) {
            acc[b][g] += w4[g][jj].x * hv.x + w4[g][jj].y * hv.y +
                         w4[g][jj].z * hv.z + w4[g][jj].w * hv.w;
          }
        }
      }
    }

    // register-halving butterfly over kc: after round r, entry ii holds
    // b = ii*2^(r+1) + (kc & (2^(r+1)-1)); final: acc[0][g] = gates of b=kc.
#pragma unroll
    for (int r = 0; r < 4; ++r) {
      int m = 1 << r;
      int kb = (kc >> r) & 1;
#pragma unroll
      for (int ii = 0; ii < (16 >> (r + 1)); ++ii) {
#pragma unroll
        for (int g = 0; g < 4; ++g) {
          float e = acc[2 * ii][g], o = acc[2 * ii + 1][g];
          float kept = kb ? o : e;
          float sent = kb ? e : o;
          acc[ii][g] = kept + __shfl_xor(sent, m, 64);
        }
      }
    }

    // update: thread owns (b = kc, col = s*8 + c); gate order i,f,g,o
    {
      float gi = acc[0][0] + xp[0];
      float gf = acc[0][1] + xp[1];
      float gg = acc[0][2] + xp[2];
      float go = acc[0][3] + xp[3];
      c_reg = sigm(gf) * c_reg + sigm(gi) * tanh_f(gg);
      float h = sigm(go) * tanh_f(c_reg);
      u64 pk = ((u64)(unsigned)(st + 1) << 32) | (u64)__float_as_uint(h);
      agent_st64(&h_ep[((size_t)(dir * Tn + xt) * 64 + bg * 16 + kc) * 256 +
                       s * 8 + c],
                 pk);
    }
  }
}

// ---------------- K4: feats = concat(hf,hb) @ W_out^T + b_out ----------------
__global__ __launch_bounds__(256) void k_feats(const u64* __restrict__ h_ep,
                                               const float* __restrict__ Wout,
                                               const float* __restrict__ bout,
                                               float* __restrict__ feats) {
  __shared__ float Wl[20 * 512];   // 40KB
  __shared__ float hlf[64 * 256];  // 64KB, XOR-swizzled

  int tid = threadIdx.x;
  int t = blockIdx.x;
  for (int i = tid; i < 20 * 512; i += 256) Wl[i] = Wout[i];

  float acc[5] = {0, 0, 0, 0, 0};
  int b = tid & 63, kg5 = tid >> 6;
  int swz = b & 7;

  for (int d = 0; d < 2; ++d) {
    __syncthreads();
    const u64* hsrc = h_ep + ((size_t)(d * Tn + t)) * 64 * 256;
#pragma unroll 8
    for (int i = 0; i < 64; ++i) {
      int idx = i * 256 + tid;
      int hb = idx >> 8, k = idx & 255;
      u64 pk = hsrc[idx];
      hlf[hb * 256 + 4 * ((k >> 2) ^ (hb & 7)) + (k & 3)] =
          __uint_as_float((unsigned)pk);
    }
    __syncthreads();
    for (int jg = 0; jg < 64; ++jg) {
      float4 hv = *(const float4*)&hlf[b * 256 + 4 * (jg ^ swz)];
#pragma unroll
      for (int kk = 0; kk < 5; ++kk) {
        int krow = kg5 * 5 + kk;
        float4 wvv = *(const float4*)&Wl[krow * 512 + d * 256 + jg * 4];
        acc[kk] += hv.x * wvv.x + hv.y * wvv.y + hv.z * wvv.z + hv.w * wvv.w;
      }
    }
  }
#pragma unroll
  for (int kk = 0; kk < 5; ++kk) {
    int krow = kg5 * 5 + kk;
    feats[((size_t)b * Tn + t) * Kt + krow] = acc[kk] + bout[krow];
  }
}

// ---------------- K5: Viterbi decode, one wave per batch element -------------
__global__ __launch_bounds__(64) void k_viterbi(const float* __restrict__ feats,
                                                const float* __restrict__ trans,
                                                const int* __restrict__ length,
                                                float* __restrict__ out) {
  __shared__ float tr[400];
  __shared__ float fv[20];
  __shared__ float term[20];
  __shared__ unsigned char bps[256][20];

  int b = blockIdx.x;
  int lane = threadIdx.x;
  for (int i = lane; i < 400; i += 64) tr[i] = trans[i];
  if (lane < 20) fv[lane] = (lane == STARTt) ? 0.0f : NEGV;
  int len = length[b];
  __syncthreads();

  for (int t = 0; t < Tn; ++t) {
    float nf = 0.0f;
    int bp = 0;
    if (lane < 20) {
      if (t < len) {
        float vmax = -3.4e38f;
        int pb = 0;
#pragma unroll
        for (int p = 0; p < 20; ++p) {
          float v = fv[p] + tr[lane * 20 + p];
          if (v > vmax) { vmax = v; pb = p; }   // strict > == first-argmax
        }
        nf = vmax + feats[((size_t)b * Tn + t) * Kt + lane];
        bp = pb;
      } else {
        nf = fv[lane];
        bp = lane;
      }
    }
    __syncthreads();
    if (lane < 20) {
      fv[lane] = nf;
      bps[t][lane] = (unsigned char)bp;
    }
    __syncthreads();
  }

  if (lane < 20) term[lane] = fv[lane] + tr[STOPt * 20 + lane];
  __syncthreads();
  if (lane == 0) {
    float smax = term[0];
    int last = 0;
    for (int p = 1; p < 20; ++p)
      if (term[p] > smax) { smax = term[p]; last = p; }
    out[b] = smax;                     // viterbi score
    int tag = last;
    for (int t = Tn - 1; t >= 0; --t) {
      out[64 + b * Tn + t] = (float)tag;
      tag = bps[t][tag];
    }
  }
}

}  // namespace

extern "C" void kernel_launch(void* const* d_in, const int* in_sizes, int n_in,
                              void* d_out, int out_size, void* d_ws,
                              size_t ws_size, hipStream_t stream) {
  const int* sentence = (const int*)d_in[0];
  const int* length = (const int*)d_in[1];
  const float* table = (const float*)d_in[2];
  const float* w_ih_f = (const float*)d_in[3];
  const float* w_hh_f = (const float*)d_in[4];
  const float* b_f = (const float*)d_in[5];
  const float* w_ih_b = (const float*)d_in[6];
  const float* w_hh_b = (const float*)d_in[7];
  const float* b_b = (const float*)d_in[8];
  const float* W_out = (const float*)d_in[9];
  const float* b_out = (const float*)d_in[10];
  const float* trans = (const float*)d_in[11];
  float* out = (float*)d_out;

  // workspace layout (floats)
  float* ws = (float*)d_ws;
  float* xproj = ws;                                  // 33,554,432 f
  u64* h_ep = (u64*)(ws + (size_t)33554432);          // 8,388,608 u64 (67 MB)
  float* Wt = ws + (size_t)33554432 + 16777216;       // 614,400 f
  float* feats = Wt + (size_t)300 * 2048;             // 327,680 f
  (void)ws_size; (void)in_sizes; (void)n_in; (void)out_size;

  k_clear<<<dim3(4096), dim3(256), 0, stream>>>((uint4*)h_ep);
  k_wt<<<dim3(2400), dim3(256), 0, stream>>>(w_ih_f, w_ih_b, Wt);
  k_xproj<<<dim3(256, 16), dim3(256), 0, stream>>>(sentence, table, Wt, b_f,
                                                   b_b, xproj);
  k_lstm<<<dim3(256), dim3(128), 0, stream>>>(w_hh_f, w_hh_b, xproj, h_ep);
  k_feats<<<dim3(256), dim3(256), 0, stream>>>(h_ep, W_out, b_out, feats);
  k_viterbi<<<dim3(64), dim3(64), 0, stream>>>(feats, trans, length, out);
}